// Round 6
// baseline (272.437 us; speedup 1.0000x reference)
//
#include <hip/hip_runtime.h>

// ---------------------------------------------------------------------------
// SGC: out[b,i,f] = sum_{j!=i} (adj^4)[i,j] * rm[b,j,f]
//   A2   = adj @ adj          (MX-fp8 e4m3 MFMA K=128, 4096^3, const scale)
//   T1   = A2 @ RM            (LDS-free direct-fragment GEMM, bf16 partials)
//   out  = A2 @ T1 - d*rm     (same, fused reduce)
//   d[i] = sum_j A2[i,j]*A2[j,i]
// Big-GEMM LDS swizzle: 16B chunk ^ (row&7) (round-4 version; rev3 variant
// measured slower with IDENTICAL conflict count -> conflicts are structural
// to the 2-read fp8 fragment pattern and not the critical pipe).
// Skinny GEMMs: fragments for 16x16x32 bf16 are 8 contiguous bf16 along K,
// loaded directly from global (row-major-along-K operands); no LDS, no
// barriers -> no m97-style barrier drain.
// ---------------------------------------------------------------------------

typedef __attribute__((ext_vector_type(8))) __bf16 bf16x8;
typedef __attribute__((ext_vector_type(8))) int intx8;
typedef __attribute__((ext_vector_type(4))) float floatx4;
typedef __attribute__((ext_vector_type(4))) short short4v;

__device__ __forceinline__ unsigned short f32_to_bf16_bits(float f) {
  unsigned int u = __float_as_uint(f);
  u += 0x7FFFu + ((u >> 16) & 1u);  // RNE
  return (unsigned short)(u >> 16);
}
__device__ __forceinline__ float bf16_bits_to_f32(unsigned short s) {
  return __uint_as_float(((unsigned int)s) << 16);
}

// OCP e4m3fn quantization, manual RNE (unbiased). Input in [0, 448].
__device__ __forceinline__ unsigned char f32_to_e4m3(float v) {
  if (!(v > 0.f)) return 0;
  unsigned u = __float_as_uint(v);
  int e = (int)((u >> 23) & 0xFF) - 127;
  if (e >= -6) {                      // normal e4m3
    unsigned m = u & 0x7FFFFF;
    unsigned keep = m >> 20;
    unsigned rem = m & 0xFFFFF;
    keep += (rem > 0x80000u) || (rem == 0x80000u && (keep & 1u));
    if (keep == 8u) { keep = 0u; e += 1; }
    return (unsigned char)(((e + 7) << 3) | keep);
  }
  if (e < -10) return 0;
  float scaled = v * 512.f;           // 2^9
  int m4 = (int)rintf(scaled);        // RNE
  if (m4 >= 8) return 0x08;
  return (unsigned char)m4;
}

__device__ __forceinline__ void gld_lds16(const void* g, void* l) {
  __builtin_amdgcn_global_load_lds(
      (const __attribute__((address_space(1))) void*)g,
      (__attribute__((address_space(3))) void*)l, 16, 0, 0);
}

// --- fused: adj fp32 -> fp8 (x 2^13) row-major AND transposed ---------------
__global__ __launch_bounds__(256) void k_prep_adj_fp8(const float* __restrict__ in,
                                                      unsigned char* __restrict__ a,
                                                      unsigned char* __restrict__ at) {
  __shared__ float tile[64][65];
  const int t = threadIdx.x;
  const int row0 = blockIdx.y * 64, col0 = blockIdx.x * 64;
  const int c4 = (t & 15) * 4;
  const int r = t >> 4;
  for (int rr = 0; rr < 64; rr += 16) {
    float4 v = *(const float4*)(in + (size_t)(row0 + r + rr) * 4096 + col0 + c4);
    tile[r + rr][c4 + 0] = v.x;
    tile[r + rr][c4 + 1] = v.y;
    tile[r + rr][c4 + 2] = v.z;
    tile[r + rr][c4 + 3] = v.w;
    unsigned char q[4];
    q[0] = f32_to_e4m3(v.x * 8192.f);
    q[1] = f32_to_e4m3(v.y * 8192.f);
    q[2] = f32_to_e4m3(v.z * 8192.f);
    q[3] = f32_to_e4m3(v.w * 8192.f);
    *(unsigned int*)(a + (size_t)(row0 + r + rr) * 4096 + col0 + c4) =
        *(const unsigned int*)q;
  }
  __syncthreads();
  for (int rr = 0; rr < 64; rr += 16) {
    const int orow = r + rr;
    unsigned char q[4];
    q[0] = f32_to_e4m3(tile[c4 + 0][orow] * 8192.f);
    q[1] = f32_to_e4m3(tile[c4 + 1][orow] * 8192.f);
    q[2] = f32_to_e4m3(tile[c4 + 2][orow] * 8192.f);
    q[3] = f32_to_e4m3(tile[c4 + 3][orow] * 8192.f);
    *(unsigned int*)(at + (size_t)(col0 + orow) * 4096 + row0 + c4) =
        *(const unsigned int*)q;
  }
}

// --- RMT[b*32+f][j] = bf16(rm[b,j,f]); also zeroes dvec ---------------------
__global__ __launch_bounds__(256) void k_build_rmt(const float* __restrict__ rm,
                                                   unsigned short* __restrict__ rmt,
                                                   float* __restrict__ dvec) {
  __shared__ unsigned short tile[64][33];
  const int b = blockIdx.x;
  const int j0 = blockIdx.y * 64;
  const int t = threadIdx.x;
  if (b == 0) {
    const int z = blockIdx.y * 256 + t;
    if (z < 4096) dvec[z] = 0.f;
  }
  #pragma unroll
  for (int p = 0; p < 2; ++p) {
    const int j = (t >> 3) + p * 32;
    const int f4 = (t & 7) * 4;
    float4 v = *(const float4*)(rm + ((size_t)b * 4096 + j0 + j) * 32 + f4);
    tile[j][f4 + 0] = f32_to_bf16_bits(v.x);
    tile[j][f4 + 1] = f32_to_bf16_bits(v.y);
    tile[j][f4 + 2] = f32_to_bf16_bits(v.z);
    tile[j][f4 + 3] = f32_to_bf16_bits(v.w);
  }
  __syncthreads();
  const int f = t >> 3, j8 = (t & 7) * 8;
  unsigned short tmp[8];
  #pragma unroll
  for (int k = 0; k < 8; ++k) tmp[k] = tile[j8 + k][f];
  *(int4*)(rmt + ((size_t)b * 32 + f) * 4096 + j0 + j8) = *(const int4*)tmp;
}

// --- d[i] = sum_j A2[i,j]*A2[j,i] ------------------------------------------
__global__ __launch_bounds__(256) void k_diag(const unsigned short* __restrict__ M2,
                                              float* __restrict__ d) {
  constexpr int P = 72;
  __shared__ __align__(16) unsigned short t1[64 * P];
  __shared__ __align__(16) unsigned short t2[64 * P];
  __shared__ float red[256];
  const int I = blockIdx.x >> 6, J = blockIdx.x & 63;
  const int t = threadIdx.x;
  for (int c = t; c < 512; c += 256) {
    const int row = c >> 3, col = (c & 7) * 8;
    *(int4*)(t1 + row * P + col) =
        *(const int4*)(M2 + (size_t)(I * 64 + row) * 4096 + J * 64 + col);
    *(int4*)(t2 + row * P + col) =
        *(const int4*)(M2 + (size_t)(J * 64 + row) * 4096 + I * 64 + col);
  }
  __syncthreads();
  const int i = t & 63, q = t >> 6;
  float s = 0.f;
  #pragma unroll
  for (int jj = 0; jj < 16; ++jj) {
    const int j = q * 16 + jj;
    s += bf16_bits_to_f32(t1[i * P + j]) * bf16_bits_to_f32(t2[j * P + i]);
  }
  red[t] = s;
  __syncthreads();
  if (t < 64) {
    const float tot = red[t] + red[t + 64] + red[t + 128] + red[t + 192];
    atomicAdd(&d[I * 64 + t], tot);
  }
}

// --- big GEMM (MX-fp8): C = A @ BT^T, 128x128 tile, BK=128 ------------------
__global__ __launch_bounds__(256) void k_gemm_big_fp8(const unsigned char* __restrict__ A,
                                                      const unsigned char* __restrict__ BT,
                                                      unsigned short* __restrict__ C,
                                                      int M, int N, int K) {
  __shared__ __align__(16) unsigned char smA[128 * 128];
  __shared__ __align__(16) unsigned char smB[128 * 128];
  const int tid = threadIdx.x;
  const int wave = tid >> 6, lane = tid & 63;
  const int quad = lane >> 4, l16 = lane & 15;
  const int wm = (wave & 1) * 64, wn = (wave >> 1) * 64;
  const int m0 = blockIdx.x * 128, n0 = blockIdx.y * 128;
  const int srow = lane >> 3;                 // 0..7
  const int gcol = ((lane & 7) ^ srow) * 16;  // swizzled byte col

  floatx4 acc[4][4];
  #pragma unroll
  for (int i = 0; i < 4; ++i)
    #pragma unroll
    for (int j = 0; j < 4; ++j) acc[i][j] = floatx4{0.f, 0.f, 0.f, 0.f};

  for (int k0 = 0; k0 < K; k0 += 128) {
    #pragma unroll
    for (int c = 0; c < 4; ++c) {
      const int ch = wave * 4 + c;  // 16 chunks of 1KB each per operand
      const int row = ch * 8 + srow;
      gld_lds16(A + (size_t)(m0 + row) * K + k0 + gcol, smA + ch * 1024);
      gld_lds16(BT + (size_t)(n0 + row) * K + k0 + gcol, smB + ch * 1024);
    }
    __syncthreads();
    intx8 af[4], bfr[4];
    #pragma unroll
    for (int i = 0; i < 4; ++i) {
      const int row = wm + i * 16 + l16;
      const int x = l16 & 7;
      const int4 lo = *(const int4*)(smA + row * 128 + (((2 * quad) ^ x) * 16));
      const int4 hi = *(const int4*)(smA + row * 128 + (((2 * quad + 1) ^ x) * 16));
      af[i] = intx8{lo.x, lo.y, lo.z, lo.w, hi.x, hi.y, hi.z, hi.w};
    }
    #pragma unroll
    for (int j = 0; j < 4; ++j) {
      const int row = wn + j * 16 + l16;
      const int x = l16 & 7;
      const int4 lo = *(const int4*)(smB + row * 128 + (((2 * quad) ^ x) * 16));
      const int4 hi = *(const int4*)(smB + row * 128 + (((2 * quad + 1) ^ x) * 16));
      bfr[j] = intx8{lo.x, lo.y, lo.z, lo.w, hi.x, hi.y, hi.z, hi.w};
    }
    #pragma unroll
    for (int i = 0; i < 4; ++i)
      #pragma unroll
      for (int j = 0; j < 4; ++j)
        acc[i][j] = __builtin_amdgcn_mfma_scale_f32_16x16x128_f8f6f4(
            af[i], bfr[j], acc[i][j], 0, 0,      // cbsz=fp8, blgp=fp8
            0, 0x7F7F7F7F, 0, 0x7F7F7F7F);       // scales = 2^0
    __syncthreads();
  }
  const float unscale = 1.4901161193847656e-8f;  // 2^-26
  #pragma unroll
  for (int i = 0; i < 4; ++i) {
    #pragma unroll
    for (int j = 0; j < 4; ++j) {
      const int rowb = m0 + wm + i * 16 + quad * 4;
      const int col = n0 + wn + j * 16 + l16;
      #pragma unroll
      for (int r = 0; r < 4; ++r)
        C[(size_t)(rowb + r) * N + col] = f32_to_bf16_bits(acc[i][j][r] * unscale);
    }
  }
}

// --- skinny split-K GEMM, LDS-free: BM=64, BN=256(=N), KC per block ---------
// Fragments loaded directly from global (both operands row-major along K).
// bf16 partials to P[kt][m][n].
template <int KC>
__global__ __launch_bounds__(256) void k_gemm_skinny(const unsigned short* __restrict__ A,
                                                     const unsigned short* __restrict__ BT,
                                                     unsigned short* __restrict__ P, int K) {
  const int tid = threadIdx.x;
  const int wave = tid >> 6, lane = tid & 63;
  const int quad = lane >> 4, l16 = lane & 15;
  const int m0 = blockIdx.x * 64;
  const int kt = blockIdx.y;
  const int wn = wave * 64;

  floatx4 acc[4][4];
  #pragma unroll
  for (int i = 0; i < 4; ++i)
    #pragma unroll
    for (int j = 0; j < 4; ++j) acc[i][j] = floatx4{0.f, 0.f, 0.f, 0.f};

  const unsigned short* Ab = A + (size_t)(m0 + l16) * K + quad * 8;
  const unsigned short* Bb = BT + (size_t)(wn + l16) * K + quad * 8;

  for (int k0 = kt * KC; k0 < kt * KC + KC; k0 += 64) {
    #pragma unroll
    for (int half = 0; half < 2; ++half) {
      const int kk = k0 + half * 32;
      bf16x8 af[4], bfr[4];
      #pragma unroll
      for (int i = 0; i < 4; ++i)
        af[i] = *(const bf16x8*)(Ab + (size_t)i * 16 * K + kk);
      #pragma unroll
      for (int j = 0; j < 4; ++j)
        bfr[j] = *(const bf16x8*)(Bb + (size_t)j * 16 * K + kk);
      #pragma unroll
      for (int i = 0; i < 4; ++i)
        #pragma unroll
        for (int j = 0; j < 4; ++j)
          acc[i][j] = __builtin_amdgcn_mfma_f32_16x16x32_bf16(af[i], bfr[j],
                                                              acc[i][j], 0, 0, 0);
    }
  }
  #pragma unroll
  for (int i = 0; i < 4; ++i) {
    #pragma unroll
    for (int j = 0; j < 4; ++j) {
      const int rowl = i * 16 + quad * 4;
      const int col = wn + j * 16 + l16;
      #pragma unroll
      for (int r = 0; r < 4; ++r)
        P[((size_t)kt * 4096 + m0 + rowl + r) * 256 + col] =
            f32_to_bf16_bits(acc[i][j][r]);
    }
  }
}

// --- reduce bf16 partials -> T1T bf16 (transposed 256 x 4096) ---------------
__global__ __launch_bounds__(256) void k_reduce_t1t(const unsigned short* __restrict__ P,
                                                    unsigned short* __restrict__ T1T) {
  __shared__ float tile[64][65];
  const int mt = blockIdx.x, nt = blockIdx.y;
  const int t = threadIdx.x;
  #pragma unroll
  for (int e = 0; e < 16; ++e) {
    const int idx = e * 256 + t;
    const int r = idx >> 6, c = idx & 63;
    float s = 0.f;
    #pragma unroll
    for (int kt = 0; kt < 8; ++kt)
      s += bf16_bits_to_f32(
          P[(size_t)kt * 1048576 + (size_t)(mt * 64 + r) * 256 + nt * 64 + c]);
    tile[r][c] = s;
  }
  __syncthreads();
  const int nr = t >> 2, mq = (t & 3) * 16;
  unsigned short tmp[16];
  #pragma unroll
  for (int k = 0; k < 16; ++k) tmp[k] = f32_to_bf16_bits(tile[mq + k][nr]);
  unsigned short* dst = T1T + (size_t)(nt * 64 + nr) * 4096 + mt * 64 + mq;
  *(int4*)(dst) = *(const int4*)(tmp);
  *(int4*)(dst + 8) = *(const int4*)(tmp + 8);
}

// --- reduce bf16 partials + fused epilogue: out = sum P - d[row]*rm ---------
__global__ __launch_bounds__(256) void k_reduce_out(const unsigned short* __restrict__ P,
                                                    const float* __restrict__ dvec,
                                                    const float* __restrict__ rm,
                                                    float* __restrict__ out) {
  const int idx = blockIdx.x * 256 + threadIdx.x;  // row*256+col
  const int row = idx >> 8, col = idx & 255;
  float s = 0.f;
  #pragma unroll
  for (int kt = 0; kt < 8; ++kt)
    s += bf16_bits_to_f32(P[(size_t)kt * 1048576 + idx]);
  const int b = col >> 5, f = col & 31;
  const size_t o = ((size_t)b * 4096 + row) * 32 + f;
  out[o] = s - dvec[row] * rm[o];
}

extern "C" void kernel_launch(void* const* d_in, const int* in_sizes, int n_in,
                              void* d_out, int out_size, void* d_ws, size_t ws_size,
                              hipStream_t stream) {
  const float* rm = (const float*)d_in[0];   // (8, 4096, 32) fp32
  const float* adj = (const float*)d_in[1];  // (4096, 4096) fp32
  float* out = (float*)d_out;
  char* ws = (char*)d_ws;

  unsigned char* A8    = (unsigned char*)(ws);              // 16 MiB (dead after big GEMM)
  unsigned char* A8T   = (unsigned char*)(ws + 16777216);   // 16 MiB (dead after big GEMM)
  unsigned short* A2bf = (unsigned short*)(ws + 67108864);  // 32 MiB
  unsigned short* RMT  = (unsigned short*)(ws + 100663296); // 2 MiB
  unsigned short* T1T  = (unsigned short*)(ws + 102760448); // 2 MiB
  float* dvec          = (float*)(ws + 104857600);          // 16 KiB
  unsigned short* Pp   = (unsigned short*)(ws);             // 16 MiB, reuses A8

  k_prep_adj_fp8<<<dim3(64, 64), 256, 0, stream>>>(adj, A8, A8T);
  k_build_rmt<<<dim3(8, 64), 256, 0, stream>>>(rm, RMT, dvec);

  // A2 = adj @ adj  (MX-fp8, constant scale)
  k_gemm_big_fp8<<<dim3(32, 32), 256, 0, stream>>>(A8, A8T, A2bf, 4096, 4096, 4096);

  // d[i] = sum_j A2[i,j] * A2[j,i]   (A8/A8T now dead; Pp reuses the space)
  k_diag<<<4096, 256, 0, stream>>>(A2bf, dvec);

  // T1 = A2 @ RM  (LDS-free split-K, bf16 partials -> T1T bf16)
  k_gemm_skinny<512><<<dim3(64, 8), 256, 0, stream>>>(A2bf, RMT, Pp, 4096);
  k_reduce_t1t<<<dim3(64, 4), 256, 0, stream>>>(Pp, T1T);

  // T2 = A2 @ T1  (LDS-free split-K, bf16 partials -> fused out = T2 - d*rm)
  k_gemm_skinny<512><<<dim3(64, 8), 256, 0, stream>>>(A2bf, T1T, Pp, 4096);
  k_reduce_out<<<4096, 256, 0, stream>>>(Pp, dvec, rm, out);
}

// Round 7
// 236.204 us; speedup vs baseline: 1.1534x; 1.1534x over previous
//
#include <hip/hip_runtime.h>

// ---------------------------------------------------------------------------
// SGC: out[b,i,f] = sum_{j!=i} (adj^4)[i,j] * rm[b,j,f]
//   A2   = adj @ adj          (MX-fp8 e4m3 MFMA K=128, 4096^3, const scale)
//   T1   = A2 @ RM            (split-K LDS dbuf GEMM, bf16 partials -> T1T)
//   out  = A2 @ T1 - d*rm     (same, fused reduce)
//   d[i] = sum_j A2[i,j]*A2[j,i]
// Lessons encoded:
//  - LDS-free fragment-direct skinny GEMM regressed 2x (16 scattered 64B
//    requests/instr); LDS staging + swizzle is the right structure (r6).
//  - fp8 LDS conflicts (8.39e6) are structural to the 2-read fragment
//    pattern, invariant under chunk permutation, and NOT the critical pipe
//    (rev3 experiment, r5). Don't touch the big GEMM's LDS scheme.
//  - Same-address split-K atomics regressed (r3): keep explicit partials.
// ---------------------------------------------------------------------------

typedef __attribute__((ext_vector_type(8))) __bf16 bf16x8;
typedef __attribute__((ext_vector_type(8))) int intx8;
typedef __attribute__((ext_vector_type(4))) float floatx4;
typedef __attribute__((ext_vector_type(4))) short short4v;

__device__ __forceinline__ unsigned short f32_to_bf16_bits(float f) {
  unsigned int u = __float_as_uint(f);
  u += 0x7FFFu + ((u >> 16) & 1u);  // RNE
  return (unsigned short)(u >> 16);
}
__device__ __forceinline__ float bf16_bits_to_f32(unsigned short s) {
  return __uint_as_float(((unsigned int)s) << 16);
}

// OCP e4m3fn quantization, manual RNE (unbiased). Input in [0, 448].
__device__ __forceinline__ unsigned char f32_to_e4m3(float v) {
  if (!(v > 0.f)) return 0;
  unsigned u = __float_as_uint(v);
  int e = (int)((u >> 23) & 0xFF) - 127;
  if (e >= -6) {                      // normal e4m3
    unsigned m = u & 0x7FFFFF;
    unsigned keep = m >> 20;
    unsigned rem = m & 0xFFFFF;
    keep += (rem > 0x80000u) || (rem == 0x80000u && (keep & 1u));
    if (keep == 8u) { keep = 0u; e += 1; }
    return (unsigned char)(((e + 7) << 3) | keep);
  }
  if (e < -10) return 0;
  float scaled = v * 512.f;           // 2^9
  int m4 = (int)rintf(scaled);        // RNE
  if (m4 >= 8) return 0x08;
  return (unsigned char)m4;
}

__device__ __forceinline__ void gld_lds16(const void* g, void* l) {
  __builtin_amdgcn_global_load_lds(
      (const __attribute__((address_space(1))) void*)g,
      (__attribute__((address_space(3))) void*)l, 16, 0, 0);
}

// --- fused: adj fp32 -> fp8 (x 2^13) row-major AND transposed ---------------
__global__ __launch_bounds__(256) void k_prep_adj_fp8(const float* __restrict__ in,
                                                      unsigned char* __restrict__ a,
                                                      unsigned char* __restrict__ at) {
  __shared__ float tile[64][65];
  const int t = threadIdx.x;
  const int row0 = blockIdx.y * 64, col0 = blockIdx.x * 64;
  const int c4 = (t & 15) * 4;
  const int r = t >> 4;
  for (int rr = 0; rr < 64; rr += 16) {
    float4 v = *(const float4*)(in + (size_t)(row0 + r + rr) * 4096 + col0 + c4);
    tile[r + rr][c4 + 0] = v.x;
    tile[r + rr][c4 + 1] = v.y;
    tile[r + rr][c4 + 2] = v.z;
    tile[r + rr][c4 + 3] = v.w;
    unsigned char q[4];
    q[0] = f32_to_e4m3(v.x * 8192.f);
    q[1] = f32_to_e4m3(v.y * 8192.f);
    q[2] = f32_to_e4m3(v.z * 8192.f);
    q[3] = f32_to_e4m3(v.w * 8192.f);
    *(unsigned int*)(a + (size_t)(row0 + r + rr) * 4096 + col0 + c4) =
        *(const unsigned int*)q;
  }
  __syncthreads();
  for (int rr = 0; rr < 64; rr += 16) {
    const int orow = r + rr;
    unsigned char q[4];
    q[0] = f32_to_e4m3(tile[c4 + 0][orow] * 8192.f);
    q[1] = f32_to_e4m3(tile[c4 + 1][orow] * 8192.f);
    q[2] = f32_to_e4m3(tile[c4 + 2][orow] * 8192.f);
    q[3] = f32_to_e4m3(tile[c4 + 3][orow] * 8192.f);
    *(unsigned int*)(at + (size_t)(col0 + orow) * 4096 + row0 + c4) =
        *(const unsigned int*)q;
  }
}

// --- RMT[b*32+f][j] = bf16(rm[b,j,f]); also zeroes dvec ---------------------
__global__ __launch_bounds__(256) void k_build_rmt(const float* __restrict__ rm,
                                                   unsigned short* __restrict__ rmt,
                                                   float* __restrict__ dvec) {
  __shared__ unsigned short tile[64][33];
  const int b = blockIdx.x;
  const int j0 = blockIdx.y * 64;
  const int t = threadIdx.x;
  if (b == 0) {
    const int z = blockIdx.y * 256 + t;
    if (z < 4096) dvec[z] = 0.f;
  }
  #pragma unroll
  for (int p = 0; p < 2; ++p) {
    const int j = (t >> 3) + p * 32;
    const int f4 = (t & 7) * 4;
    float4 v = *(const float4*)(rm + ((size_t)b * 4096 + j0 + j) * 32 + f4);
    tile[j][f4 + 0] = f32_to_bf16_bits(v.x);
    tile[j][f4 + 1] = f32_to_bf16_bits(v.y);
    tile[j][f4 + 2] = f32_to_bf16_bits(v.z);
    tile[j][f4 + 3] = f32_to_bf16_bits(v.w);
  }
  __syncthreads();
  const int f = t >> 3, j8 = (t & 7) * 8;
  unsigned short tmp[8];
  #pragma unroll
  for (int k = 0; k < 8; ++k) tmp[k] = tile[j8 + k][f];
  *(int4*)(rmt + ((size_t)b * 32 + f) * 4096 + j0 + j8) = *(const int4*)tmp;
}

// --- d[i] = sum_j A2[i,j]*A2[j,i] ------------------------------------------
__global__ __launch_bounds__(256) void k_diag(const unsigned short* __restrict__ M2,
                                              float* __restrict__ d) {
  constexpr int P = 72;
  __shared__ __align__(16) unsigned short t1[64 * P];
  __shared__ __align__(16) unsigned short t2[64 * P];
  __shared__ float red[256];
  const int I = blockIdx.x >> 6, J = blockIdx.x & 63;
  const int t = threadIdx.x;
  for (int c = t; c < 512; c += 256) {
    const int row = c >> 3, col = (c & 7) * 8;
    *(int4*)(t1 + row * P + col) =
        *(const int4*)(M2 + (size_t)(I * 64 + row) * 4096 + J * 64 + col);
    *(int4*)(t2 + row * P + col) =
        *(const int4*)(M2 + (size_t)(J * 64 + row) * 4096 + I * 64 + col);
  }
  __syncthreads();
  const int i = t & 63, q = t >> 6;
  float s = 0.f;
  #pragma unroll
  for (int jj = 0; jj < 16; ++jj) {
    const int j = q * 16 + jj;
    s += bf16_bits_to_f32(t1[i * P + j]) * bf16_bits_to_f32(t2[j * P + i]);
  }
  red[t] = s;
  __syncthreads();
  if (t < 64) {
    const float tot = red[t] + red[t + 64] + red[t + 128] + red[t + 192];
    atomicAdd(&d[I * 64 + t], tot);
  }
}

// --- big GEMM (MX-fp8): C = A @ BT^T, 128x128 tile, BK=128 ------------------
__global__ __launch_bounds__(256) void k_gemm_big_fp8(const unsigned char* __restrict__ A,
                                                      const unsigned char* __restrict__ BT,
                                                      unsigned short* __restrict__ C,
                                                      int M, int N, int K) {
  __shared__ __align__(16) unsigned char smA[128 * 128];
  __shared__ __align__(16) unsigned char smB[128 * 128];
  const int tid = threadIdx.x;
  const int wave = tid >> 6, lane = tid & 63;
  const int quad = lane >> 4, l16 = lane & 15;
  const int wm = (wave & 1) * 64, wn = (wave >> 1) * 64;
  const int m0 = blockIdx.x * 128, n0 = blockIdx.y * 128;
  const int srow = lane >> 3;                 // 0..7
  const int gcol = ((lane & 7) ^ srow) * 16;  // swizzled byte col

  floatx4 acc[4][4];
  #pragma unroll
  for (int i = 0; i < 4; ++i)
    #pragma unroll
    for (int j = 0; j < 4; ++j) acc[i][j] = floatx4{0.f, 0.f, 0.f, 0.f};

  for (int k0 = 0; k0 < K; k0 += 128) {
    #pragma unroll
    for (int c = 0; c < 4; ++c) {
      const int ch = wave * 4 + c;  // 16 chunks of 1KB each per operand
      const int row = ch * 8 + srow;
      gld_lds16(A + (size_t)(m0 + row) * K + k0 + gcol, smA + ch * 1024);
      gld_lds16(BT + (size_t)(n0 + row) * K + k0 + gcol, smB + ch * 1024);
    }
    __syncthreads();
    intx8 af[4], bfr[4];
    #pragma unroll
    for (int i = 0; i < 4; ++i) {
      const int row = wm + i * 16 + l16;
      const int x = l16 & 7;
      const int4 lo = *(const int4*)(smA + row * 128 + (((2 * quad) ^ x) * 16));
      const int4 hi = *(const int4*)(smA + row * 128 + (((2 * quad + 1) ^ x) * 16));
      af[i] = intx8{lo.x, lo.y, lo.z, lo.w, hi.x, hi.y, hi.z, hi.w};
    }
    #pragma unroll
    for (int j = 0; j < 4; ++j) {
      const int row = wn + j * 16 + l16;
      const int x = l16 & 7;
      const int4 lo = *(const int4*)(smB + row * 128 + (((2 * quad) ^ x) * 16));
      const int4 hi = *(const int4*)(smB + row * 128 + (((2 * quad + 1) ^ x) * 16));
      bfr[j] = intx8{lo.x, lo.y, lo.z, lo.w, hi.x, hi.y, hi.z, hi.w};
    }
    #pragma unroll
    for (int i = 0; i < 4; ++i)
      #pragma unroll
      for (int j = 0; j < 4; ++j)
        acc[i][j] = __builtin_amdgcn_mfma_scale_f32_16x16x128_f8f6f4(
            af[i], bfr[j], acc[i][j], 0, 0,      // cbsz=fp8, blgp=fp8
            0, 0x7F7F7F7F, 0, 0x7F7F7F7F);       // scales = 2^0
    __syncthreads();
  }
  const float unscale = 1.4901161193847656e-8f;  // 2^-26
  #pragma unroll
  for (int i = 0; i < 4; ++i) {
    #pragma unroll
    for (int j = 0; j < 4; ++j) {
      const int rowb = m0 + wm + i * 16 + quad * 4;
      const int col = n0 + wn + j * 16 + l16;
      #pragma unroll
      for (int r = 0; r < 4; ++r)
        C[(size_t)(rowb + r) * N + col] = f32_to_bf16_bits(acc[i][j][r] * unscale);
    }
  }
}

// --- skinny split-K GEMM: BM=64, BN=128, BK=64, KC=512, LDS double-buffer ---
// grid (64 m-tiles, 2 n-tiles, 8 kt). bf16 partials P[kt][4096][256].
template <int KC>
__global__ __launch_bounds__(256) void k_gemm_skinny(const unsigned short* __restrict__ A,
                                                     const unsigned short* __restrict__ BT,
                                                     unsigned short* __restrict__ P, int K) {
  constexpr int NITER = KC / 64;
  __shared__ __align__(16) unsigned short smA[2][64 * 64];
  __shared__ __align__(16) unsigned short smB[2][128 * 64];
  const int tid = threadIdx.x;
  const int wave = tid >> 6, lane = tid & 63;
  const int quad = lane >> 4, l16 = lane & 15;
  const int m0 = blockIdx.x * 64;
  const int n0 = blockIdx.y * 128;
  const int kt = blockIdx.z;
  const int wm = (wave & 1) * 32, wn = (wave >> 1) * 64;
  const int srow = lane >> 3;
  const int gcol = ((lane & 7) ^ srow) * 8;
  const int kbeg = kt * KC;

  floatx4 acc[2][4];
  #pragma unroll
  for (int i = 0; i < 2; ++i)
    #pragma unroll
    for (int j = 0; j < 4; ++j) acc[i][j] = floatx4{0.f, 0.f, 0.f, 0.f};

  // stage(buf, k0): 24 chunks of 1KB (A:0-7, B:8-23), 6 per wave
  auto stage = [&](int buf, int k0) {
    #pragma unroll
    for (int u = 0; u < 6; ++u) {
      const int ch = wave * 6 + u;
      if (ch < 8) {
        const int row = ch * 8 + srow;
        gld_lds16(A + (size_t)(m0 + row) * K + k0 + gcol,
                  &smA[buf][ch * 512]);
      } else {
        const int c2 = ch - 8;
        const int row = c2 * 8 + srow;
        gld_lds16(BT + (size_t)(n0 + row) * K + k0 + gcol,
                  &smB[buf][c2 * 512]);
      }
    }
  };

  stage(0, kbeg);
  for (int it = 0; it < NITER; ++it) {
    const int buf = it & 1;
    __syncthreads();                      // buf staged (drains vmcnt)
    if (it + 1 < NITER) stage(buf ^ 1, kbeg + (it + 1) * 64);  // prefetch
    #pragma unroll
    for (int kk = 0; kk < 64; kk += 32) {
      const int g8 = quad + (kk >> 3);
      bf16x8 af[2], bfr[4];
      #pragma unroll
      for (int i = 0; i < 2; ++i) {
        const int row = wm + i * 16 + l16;
        af[i] = *(const bf16x8*)(&smA[buf][row * 64 + ((g8 ^ (row & 7)) * 8)]);
      }
      #pragma unroll
      for (int j = 0; j < 4; ++j) {
        const int row = wn + j * 16 + l16;
        bfr[j] = *(const bf16x8*)(&smB[buf][row * 64 + ((g8 ^ (row & 7)) * 8)]);
      }
      #pragma unroll
      for (int i = 0; i < 2; ++i)
        #pragma unroll
        for (int j = 0; j < 4; ++j)
          acc[i][j] = __builtin_amdgcn_mfma_f32_16x16x32_bf16(af[i], bfr[j],
                                                              acc[i][j], 0, 0, 0);
    }
  }
  #pragma unroll
  for (int i = 0; i < 2; ++i) {
    #pragma unroll
    for (int j = 0; j < 4; ++j) {
      const int rowl = wm + i * 16 + quad * 4;
      const int col = n0 + wn + j * 16 + l16;
      #pragma unroll
      for (int r = 0; r < 4; ++r)
        P[((size_t)kt * 4096 + m0 + rowl + r) * 256 + col] =
            f32_to_bf16_bits(acc[i][j][r]);
    }
  }
}

// --- reduce bf16 partials -> T1T bf16 (transposed 256 x 4096) ---------------
__global__ __launch_bounds__(256) void k_reduce_t1t(const unsigned short* __restrict__ P,
                                                    unsigned short* __restrict__ T1T) {
  __shared__ float tile[64][65];
  const int mt = blockIdx.x, nt = blockIdx.y;
  const int t = threadIdx.x;
  #pragma unroll
  for (int e = 0; e < 16; ++e) {
    const int idx = e * 256 + t;
    const int r = idx >> 6, c = idx & 63;
    float s = 0.f;
    #pragma unroll
    for (int kt = 0; kt < 8; ++kt)
      s += bf16_bits_to_f32(
          P[(size_t)kt * 1048576 + (size_t)(mt * 64 + r) * 256 + nt * 64 + c]);
    tile[r][c] = s;
  }
  __syncthreads();
  const int nr = t >> 2, mq = (t & 3) * 16;
  unsigned short tmp[16];
  #pragma unroll
  for (int k = 0; k < 16; ++k) tmp[k] = f32_to_bf16_bits(tile[mq + k][nr]);
  unsigned short* dst = T1T + (size_t)(nt * 64 + nr) * 4096 + mt * 64 + mq;
  *(int4*)(dst) = *(const int4*)(tmp);
  *(int4*)(dst + 8) = *(const int4*)(tmp + 8);
}

// --- reduce bf16 partials + fused epilogue: out = sum P - d[row]*rm ---------
__global__ __launch_bounds__(256) void k_reduce_out(const unsigned short* __restrict__ P,
                                                    const float* __restrict__ dvec,
                                                    const float* __restrict__ rm,
                                                    float* __restrict__ out) {
  const int idx = blockIdx.x * 256 + threadIdx.x;  // row*256+col
  const int row = idx >> 8, col = idx & 255;
  float s = 0.f;
  #pragma unroll
  for (int kt = 0; kt < 8; ++kt)
    s += bf16_bits_to_f32(P[(size_t)kt * 1048576 + idx]);
  const int b = col >> 5, f = col & 31;
  const size_t o = ((size_t)b * 4096 + row) * 32 + f;
  out[o] = s - dvec[row] * rm[o];
}

extern "C" void kernel_launch(void* const* d_in, const int* in_sizes, int n_in,
                              void* d_out, int out_size, void* d_ws, size_t ws_size,
                              hipStream_t stream) {
  const float* rm = (const float*)d_in[0];   // (8, 4096, 32) fp32
  const float* adj = (const float*)d_in[1];  // (4096, 4096) fp32
  float* out = (float*)d_out;
  char* ws = (char*)d_ws;

  unsigned char* A8    = (unsigned char*)(ws);              // 16 MiB (dead after big GEMM)
  unsigned char* A8T   = (unsigned char*)(ws + 16777216);   // 16 MiB (dead after big GEMM)
  unsigned short* A2bf = (unsigned short*)(ws + 67108864);  // 32 MiB
  unsigned short* RMT  = (unsigned short*)(ws + 100663296); // 2 MiB
  unsigned short* T1T  = (unsigned short*)(ws + 102760448); // 2 MiB
  float* dvec          = (float*)(ws + 104857600);          // 16 KiB
  unsigned short* Pp   = (unsigned short*)(ws);             // 16 MiB, reuses A8

  k_prep_adj_fp8<<<dim3(64, 64), 256, 0, stream>>>(adj, A8, A8T);
  k_build_rmt<<<dim3(8, 64), 256, 0, stream>>>(rm, RMT, dvec);

  // A2 = adj @ adj  (MX-fp8, constant scale)
  k_gemm_big_fp8<<<dim3(32, 32), 256, 0, stream>>>(A8, A8T, A2bf, 4096, 4096, 4096);

  // d[i] = sum_j A2[i,j] * A2[j,i]   (A8/A8T now dead; Pp reuses the space)
  k_diag<<<4096, 256, 0, stream>>>(A2bf, dvec);

  // T1 = A2 @ RM  (split-K dbuf LDS, bf16 partials -> T1T bf16)
  k_gemm_skinny<512><<<dim3(64, 2, 8), 256, 0, stream>>>(A2bf, RMT, Pp, 4096);
  k_reduce_t1t<<<dim3(64, 4), 256, 0, stream>>>(Pp, T1T);

  // T2 = A2 @ T1  (split-K dbuf LDS, bf16 partials -> fused out = T2 - d*rm)
  k_gemm_skinny<512><<<dim3(64, 2, 8), 256, 0, stream>>>(A2bf, T1T, Pp, 4096);
  k_reduce_out<<<4096, 256, 0, stream>>>(Pp, dvec, rm, out);
}